// Round 1
// 678.978 us; speedup vs baseline: 1.0625x; 1.0625x over previous
//
#include <hip/hip_runtime.h>
#include <hip/hip_bf16.h>

#define N_NODES 170000
#define N_EDGES 1200000
#define SCAN_PAD 171008          // 167 blocks * 1024
#define NB_SCAN 167

typedef short bf16x8 __attribute__((ext_vector_type(8)));
typedef float f32x4 __attribute__((ext_vector_type(4)));

__device__ __forceinline__ void bf_split(float v, __hip_bfloat16& h, __hip_bfloat16& l)
{
    h = __float2bfloat16(v);
    l = __float2bfloat16(v - __bfloat162float(h));
}

// ---------------- histogram: in/out degree counts (int atomics) ----------------
// The cnt_in atomic's RETURN VALUE is the edge's rank within its dst bucket.
// Recording it here lets scatter_kernel run atomic-free (rank-record trick):
// total agent-scope RMWs drop 3.6M -> 2.4M (each is a 32B fabric transaction,
// the measured bottleneck: WRITE_SIZE = 2.4M*32B at 25.5 GT/s).
__global__ __launch_bounds__(256) void hist_kernel(
    const int* __restrict__ src, const int* __restrict__ dst,
    int* __restrict__ cnt_out, int* __restrict__ cnt_in,
    int* __restrict__ rank, int nedges)
{
    int i = blockIdx.x * 256 + threadIdx.x;
    if (i < nedges) {
        atomicAdd(&cnt_out[src[i]], 1);
        rank[i] = atomicAdd(&cnt_in[dst[i]], 1);
    }
}

// ---------------- norm = 1/sqrt(max(cnt,1)) ----------------
__global__ __launch_bounds__(256) void norm_kernel(
    const int* __restrict__ cnt, float* __restrict__ norm, int n)
{
    int i = blockIdx.x * 256 + threadIdx.x;
    if (i < n) norm[i] = rsqrtf(fmaxf((float)cnt[i], 1.0f));
}

// ---------------- fp32 -> bf16 row cast (feat) ----------------
__global__ __launch_bounds__(256) void f2bf_kernel(
    const float* __restrict__ in, __hip_bfloat16* __restrict__ outp, int n8)
{
    int i = blockIdx.x * 256 + threadIdx.x;
    if (i >= n8) return;
    float4 a = *(const float4*)&in[(size_t)i * 8];
    float4 b = *(const float4*)&in[(size_t)i * 8 + 4];
    float4 packed;
    __hip_bfloat162* p = (__hip_bfloat162*)&packed;
    p[0].x = __float2bfloat16(a.x); p[0].y = __float2bfloat16(a.y);
    p[1].x = __float2bfloat16(a.z); p[1].y = __float2bfloat16(a.w);
    p[2].x = __float2bfloat16(b.x); p[2].y = __float2bfloat16(b.y);
    p[3].x = __float2bfloat16(b.z); p[3].y = __float2bfloat16(b.w);
    *(float4*)&outp[(size_t)i * 8] = packed;
}

// ---------------- W (K x Nout fp32) -> transposed split planes Wt[n][k] bf16 ----------------
__global__ __launch_bounds__(256) void wsplit_kernel(
    const float* __restrict__ W, int nout,
    __hip_bfloat16* __restrict__ Whi, __hip_bfloat16* __restrict__ Wlo)
{
    int i = blockIdx.x * 256 + threadIdx.x;   // over 128*nout
    if (i >= 128 * nout) return;
    int k = i / nout, n = i - k * nout;
    float v = W[i];
    __hip_bfloat16 h, l;
    bf_split(v, h, l);
    Whi[n * 128 + k] = h;
    Wlo[n * 128 + k] = l;
}

// ---------------- 3-phase exclusive scan of cnt_in -> row_start ----------------
__global__ __launch_bounds__(256) void scan1_kernel(
    const int* __restrict__ in, int* __restrict__ partial,
    int* __restrict__ blockSums, int n)
{
    __shared__ int sdata[256];
    int t = threadIdx.x;
    int base = blockIdx.x * 1024 + t * 4;
    int4 v = make_int4(0, 0, 0, 0);
    if (base + 3 < n) v = *(const int4*)&in[base];
    else {
        if (base + 0 < n) v.x = in[base + 0];
        if (base + 1 < n) v.y = in[base + 1];
        if (base + 2 < n) v.z = in[base + 2];
        if (base + 3 < n) v.w = in[base + 3];
    }
    int tsum = v.x + v.y + v.z + v.w;
    sdata[t] = tsum;
    __syncthreads();
    for (int off = 1; off < 256; off <<= 1) {
        int add = 0;
        if (t >= off) add = sdata[t - off];
        __syncthreads();
        if (t >= off) sdata[t] += add;
        __syncthreads();
    }
    int excl = sdata[t] - tsum;
    int4 o;
    o.x = excl;
    o.y = o.x + v.x;
    o.z = o.y + v.y;
    o.w = o.z + v.z;
    *(int4*)&partial[base] = o;   // partial buffer padded to SCAN_PAD+4
    if (t == 255) blockSums[blockIdx.x] = sdata[255];
}

__global__ __launch_bounds__(256) void scan2_kernel(int* __restrict__ blockSums, int nb)
{
    __shared__ int sdata[256];
    int t = threadIdx.x;
    int val = (t < nb) ? blockSums[t] : 0;
    sdata[t] = val;
    __syncthreads();
    for (int off = 1; off < 256; off <<= 1) {
        int add = 0;
        if (t >= off) add = sdata[t - off];
        __syncthreads();
        if (t >= off) sdata[t] += add;
        __syncthreads();
    }
    if (t < nb) blockSums[t] = sdata[t] - val;   // exclusive
}

__global__ __launch_bounds__(256) void scan3_kernel(
    int* __restrict__ row_start, const int* __restrict__ blockSums)
{
    int off = blockSums[blockIdx.x];
    int base = blockIdx.x * 1024 + threadIdx.x * 4;
    int4 v = *(const int4*)&row_start[base];
    v.x += off; v.y += off; v.z += off; v.w += off;
    *(int4*)&row_start[base] = v;
}

// ---------------- scatter src ids into dst-sorted CSR (atomic-free) ----------------
// rank[i] (recorded in hist_kernel) + row_start gives each edge a unique slot.
// row_start reads are random 4B loads over 680KB -> L2-resident, cheap.
__global__ __launch_bounds__(256) void scatter_kernel(
    const int* __restrict__ src, const int* __restrict__ dst,
    const int* __restrict__ rank, const int* __restrict__ row_start,
    int* __restrict__ csr, int nedges)
{
    int i = blockIdx.x * 256 + threadIdx.x;
    if (i < nedges) {
        csr[row_start[dst[i]] + rank[i]] = src[i];
    }
}

// ---------------- pull aggregation: 16-lane group per dst row, bf16 features ----
// Accumulates fp32. For W=128 emits SPLIT bf16 planes (hi+lo ~ fp32 precision,
// feeds the MFMA GEMM); for W=64 (final layer) emits fp32 + bias.
template<int W, bool SCALE_SRC, bool SPLIT_OUT, bool BIAS>
__global__ __launch_bounds__(256) void gather_kernel(
    const __hip_bfloat16* __restrict__ h, const int* __restrict__ csr,
    const int* __restrict__ row_start, const float* __restrict__ norm_out,
    const float* __restrict__ norm_in, const float* __restrict__ bias,
    float* __restrict__ outf, __hip_bfloat16* __restrict__ ohi,
    __hip_bfloat16* __restrict__ olo)
{
    int tid = blockIdx.x * 256 + threadIdx.x;
    int row = tid >> 4;                 // 16 lanes per row
    int l = threadIdx.x & 15;           // lane within group
    int gbase = threadIdx.x & 48;       // group's base lane within the wave
    if (row >= N_NODES) return;
    int beg = row_start[row];
    int end = row_start[row + 1];
    float acc[8] = {};
    for (int j = beg; j < end; j += 16) {
        int cnt = min(16, end - j);
        int sv = 0;
        float nv = 0.f;
        if (j + l < end) {
            sv = csr[j + l];                       // coalesced edge-id load
            if (SCALE_SRC) nv = norm_out[sv];
        }
        for (int i = 0; i < cnt; i++) {
            int s = __shfl(sv, gbase + i);
            if (W == 128) {
                float4 raw = *(const float4*)(h + (size_t)s * 128 + l * 8);
                const __hip_bfloat162* pp = (const __hip_bfloat162*)&raw;
                float2 f0 = __bfloat1622float2(pp[0]);
                float2 f1 = __bfloat1622float2(pp[1]);
                float2 f2 = __bfloat1622float2(pp[2]);
                float2 f3 = __bfloat1622float2(pp[3]);
                if (SCALE_SRC) {
                    float sc = __shfl(nv, gbase + i);
                    acc[0] += f0.x * sc; acc[1] += f0.y * sc;
                    acc[2] += f1.x * sc; acc[3] += f1.y * sc;
                    acc[4] += f2.x * sc; acc[5] += f2.y * sc;
                    acc[6] += f3.x * sc; acc[7] += f3.y * sc;
                } else {
                    acc[0] += f0.x; acc[1] += f0.y;
                    acc[2] += f1.x; acc[3] += f1.y;
                    acc[4] += f2.x; acc[5] += f2.y;
                    acc[6] += f3.x; acc[7] += f3.y;
                }
            } else {
                float2 raw = *(const float2*)(h + (size_t)s * 64 + l * 4);
                const __hip_bfloat162* pp = (const __hip_bfloat162*)&raw;
                float2 f0 = __bfloat1622float2(pp[0]);
                float2 f1 = __bfloat1622float2(pp[1]);
                acc[0] += f0.x; acc[1] += f0.y;
                acc[2] += f1.x; acc[3] += f1.y;
            }
        }
    }
    float ni = norm_in[row];
    if (W == 128 && SPLIT_OUT) {
        float4 ph, pl;
        __hip_bfloat16* hp = (__hip_bfloat16*)&ph;
        __hip_bfloat16* lp = (__hip_bfloat16*)&pl;
        #pragma unroll
        for (int j = 0; j < 8; j++) bf_split(acc[j] * ni, hp[j], lp[j]);
        *(float4*)(ohi + (size_t)row * 128 + l * 8) = ph;
        *(float4*)(olo + (size_t)row * 128 + l * 8) = pl;
    } else if (W == 64) {
        float4 o0 = make_float4(acc[0] * ni, acc[1] * ni, acc[2] * ni, acc[3] * ni);
        if (BIAS) {
            float4 b = *(const float4*)&bias[l * 4];
            o0.x += b.x; o0.y += b.y; o0.z += b.z; o0.w += b.w;
        }
        *(float4*)&outf[(size_t)row * 64 + l * 4] = o0;
    }
}

// ---------------- MFMA GEMM: out = act(A @ W + b) * rowscale ----------------
// A in split bf16 planes (hi+lo ~ fp32), Wt in transposed split planes [n][k].
// 3-MFMA split product: hi*hi + lo*hi + hi*lo (lo*lo dropped, ~2^-16 rel).
// Per wave: two 16-row tiles x NT 16-col tiles, K=128 in 4 chunks of 32.
// No LDS, no barriers; W planes stay L1/L2-resident.
// #pragma unroll 1 on kc: prevents full-unroll load hoisting (R1 spill lesson).
template<int NT, bool RELU, bool BIAS, bool RS, bool SPLIT_OUT>
__global__ __launch_bounds__(256) void mfma_matmul_kernel(
    const __hip_bfloat16* __restrict__ Ahi, const __hip_bfloat16* __restrict__ Alo,
    const __hip_bfloat16* __restrict__ Wthi, const __hip_bfloat16* __restrict__ Wtlo,
    const float* __restrict__ bias, const float* __restrict__ rowscale,
    __hip_bfloat16* __restrict__ outhi, __hip_bfloat16* __restrict__ outlo,
    int nrows)
{
    const int OUTW = NT * 16;
    const int wave = threadIdx.x >> 6;
    const int lane = threadIdx.x & 63;
    const int n = lane & 15;       // col within tile (B/D); also row within tile for A
    const int q = lane >> 4;       // quad
    const int r0 = blockIdx.x * 128 + wave * 32;
    if (r0 >= nrows) return;
    const bool t1 = (r0 + 16) < nrows;          // nrows % 16 == 0 -> tiles are full
    const size_t a0off = (size_t)(r0 + n) * 128 + q * 8;
    const size_t a1off = (size_t)(t1 ? (r0 + 16 + n) : (r0 + n)) * 128 + q * 8;
    const size_t bbase = (size_t)n * 128 + q * 8;

    f32x4 acc0[NT], acc1[NT];
    const f32x4 zero = {0.f, 0.f, 0.f, 0.f};
    #pragma unroll
    for (int ct = 0; ct < NT; ct++) { acc0[ct] = zero; acc1[ct] = zero; }

    #pragma unroll 1
    for (int kc = 0; kc < 4; kc++) {
        bf16x8 ah0 = *(const bf16x8*)(Ahi + a0off + kc * 32);
        bf16x8 al0 = *(const bf16x8*)(Alo + a0off + kc * 32);
        bf16x8 ah1 = *(const bf16x8*)(Ahi + a1off + kc * 32);
        bf16x8 al1 = *(const bf16x8*)(Alo + a1off + kc * 32);
        #pragma unroll
        for (int ct = 0; ct < NT; ct++) {
            bf16x8 bh = *(const bf16x8*)(Wthi + (size_t)ct * 2048 + bbase + kc * 32);
            bf16x8 bl = *(const bf16x8*)(Wtlo + (size_t)ct * 2048 + bbase + kc * 32);
            acc0[ct] = __builtin_amdgcn_mfma_f32_16x16x32_bf16(ah0, bh, acc0[ct], 0, 0, 0);
            acc0[ct] = __builtin_amdgcn_mfma_f32_16x16x32_bf16(al0, bh, acc0[ct], 0, 0, 0);
            acc0[ct] = __builtin_amdgcn_mfma_f32_16x16x32_bf16(ah0, bl, acc0[ct], 0, 0, 0);
            acc1[ct] = __builtin_amdgcn_mfma_f32_16x16x32_bf16(ah1, bh, acc1[ct], 0, 0, 0);
            acc1[ct] = __builtin_amdgcn_mfma_f32_16x16x32_bf16(al1, bh, acc1[ct], 0, 0, 0);
            acc1[ct] = __builtin_amdgcn_mfma_f32_16x16x32_bf16(ah1, bl, acc1[ct], 0, 0, 0);
        }
    }

    float bcol[NT];
    #pragma unroll
    for (int ct = 0; ct < NT; ct++) bcol[ct] = BIAS ? bias[ct * 16 + n] : 0.f;

    // tile 0: rows r0 + q*4 + r
    #pragma unroll
    for (int r = 0; r < 4; r++) {
        int grow = r0 + q * 4 + r;
        float rs = RS ? rowscale[grow] : 1.f;
        #pragma unroll
        for (int ct = 0; ct < NT; ct++) {
            float v = acc0[ct][r] + bcol[ct];
            if (RELU) v = fmaxf(v, 0.f);
            v *= rs;
            size_t o = (size_t)grow * OUTW + ct * 16 + n;
            if (SPLIT_OUT) {
                __hip_bfloat16 h, l;
                bf_split(v, h, l);
                outhi[o] = h; outlo[o] = l;
            } else {
                outhi[o] = __float2bfloat16(v);
            }
        }
    }
    if (t1) {
        #pragma unroll
        for (int r = 0; r < 4; r++) {
            int grow = r0 + 16 + q * 4 + r;
            float rs = RS ? rowscale[grow] : 1.f;
            #pragma unroll
            for (int ct = 0; ct < NT; ct++) {
                float v = acc1[ct][r] + bcol[ct];
                if (RELU) v = fmaxf(v, 0.f);
                v *= rs;
                size_t o = (size_t)grow * OUTW + ct * 16 + n;
                if (SPLIT_OUT) {
                    __hip_bfloat16 h, l;
                    bf_split(v, h, l);
                    outhi[o] = h; outlo[o] = l;
                } else {
                    outhi[o] = __float2bfloat16(v);
                }
            }
        }
    }
}

extern "C" void kernel_launch(void* const* d_in, const int* in_sizes, int n_in,
                              void* d_out, int out_size, void* d_ws, size_t ws_size,
                              hipStream_t stream)
{
    const float* feat = (const float*)d_in[0];
    const int* src    = (const int*)d_in[1];
    const int* dst    = (const int*)d_in[2];
    const float* W0   = (const float*)d_in[3];
    const float* b0   = (const float*)d_in[4];
    const float* W1   = (const float*)d_in[5];
    const float* b1   = (const float*)d_in[6];
    const float* W2   = (const float*)d_in[7];
    const float* b2   = (const float*)d_in[8];
    float* out = (float*)d_out;

    const int N = N_NODES;
    const int E = N_EDGES;

    // ---- workspace layout ----
    char* ws = (char*)d_ws;
    float* norm_out = (float*)ws;                    // N
    float* norm_in  = norm_out + N;                  // N
    int* cnt_out    = (int*)(norm_in + N);           // N
    int* cnt_in     = cnt_out + N;                   // N
    int* row_start  = cnt_in + N;                    // SCAN_PAD + 4
    int* blockSums  = row_start + (SCAN_PAD + 4);    // 268 (keeps 16B alignment)
    int* csr        = blockSums + 268;               // E
    __hip_bfloat16* Wt0hi = (__hip_bfloat16*)(csr + E);   // 16384 each
    __hip_bfloat16* Wt0lo = Wt0hi + 16384;
    __hip_bfloat16* Wt1hi = Wt0lo + 16384;
    __hip_bfloat16* Wt1lo = Wt1hi + 16384;
    __hip_bfloat16* Wt2hi = Wt1lo + 16384;           // 8192 each
    __hip_bfloat16* Wt2lo = Wt2hi + 8192;
    __hip_bfloat16* bfbuf = Wt2lo + 8192;            // N*128 (featbf -> h1bf -> tbf)
    __hip_bfloat16* Ahi   = bfbuf + (size_t)N * 128; // N*128
    __hip_bfloat16* Alo   = Ahi + (size_t)N * 128;   // N*128
    // rank aliases Ahi: rank is dead after scatter_kernel, and Ahi is first
    // written by gather1 which runs strictly after scatter (stream-ordered).
    int* rank = (int*)Ahi;                           // E ints (4.8MB of Ahi's 43.5MB)

    // ---- CSR build + casts/splits ----
    hipMemsetAsync(cnt_out, 0, 2 * (size_t)N * sizeof(int), stream);
    hist_kernel<<<(E + 255) / 256, 256, 0, stream>>>(src, dst, cnt_out, cnt_in, rank, E);
    norm_kernel<<<(2 * N + 255) / 256, 256, 0, stream>>>(cnt_out, norm_out, 2 * N);
    scan1_kernel<<<NB_SCAN, 256, 0, stream>>>(cnt_in, row_start, blockSums, N);
    scan2_kernel<<<1, 256, 0, stream>>>(blockSums, NB_SCAN);
    scan3_kernel<<<NB_SCAN, 256, 0, stream>>>(row_start, blockSums);
    scatter_kernel<<<(E + 255) / 256, 256, 0, stream>>>(src, dst, rank, row_start, csr, E);
    f2bf_kernel<<<(N * 16 + 255) / 256, 256, 0, stream>>>(feat, bfbuf, N * 16);
    wsplit_kernel<<<64, 256, 0, stream>>>(W0, 128, Wt0hi, Wt0lo);
    wsplit_kernel<<<64, 256, 0, stream>>>(W1, 128, Wt1hi, Wt1lo);
    wsplit_kernel<<<32, 256, 0, stream>>>(W2, 64, Wt2hi, Wt2lo);

    const int gatherBlocks = (N * 16 + 255) / 256;   // 16 lanes/row
    const int mmBlocks = (N + 127) / 128;            // 128 rows/block (2 tiles/wave)

    // ---- Layer 1: agg(featbf*no)*ni -> A split; relu(A@W0+b0)*no -> h1bf
    gather_kernel<128, true, true, false><<<gatherBlocks, 256, 0, stream>>>(
        bfbuf, csr, row_start, norm_out, norm_in, nullptr, nullptr, Ahi, Alo);
    mfma_matmul_kernel<8, true, true, true, false><<<mmBlocks, 256, 0, stream>>>(
        Ahi, Alo, Wt0hi, Wt0lo, b0, norm_out, bfbuf, nullptr, N);

    // ---- Layer 2: agg(h1bf)*ni -> A split; relu(A@W1+b1)*no -> A split (in-place)
    gather_kernel<128, false, true, false><<<gatherBlocks, 256, 0, stream>>>(
        bfbuf, csr, row_start, nullptr, norm_in, nullptr, nullptr, Ahi, Alo);
    mfma_matmul_kernel<8, true, true, true, true><<<mmBlocks, 256, 0, stream>>>(
        Ahi, Alo, Wt1hi, Wt1lo, b1, norm_out, Ahi, Alo, N);

    // ---- Layer 3 (commuted): tbf = bf16(h2@W2); out = agg(tbf)*ni + b2
    mfma_matmul_kernel<4, false, false, false, false><<<mmBlocks, 256, 0, stream>>>(
        Ahi, Alo, Wt2hi, Wt2lo, nullptr, nullptr, bfbuf, nullptr, N);
    gather_kernel<64, false, false, true><<<gatherBlocks, 256, 0, stream>>>(
        bfbuf, csr, row_start, nullptr, norm_in, b2, out, nullptr, nullptr);
}

// Round 2
// 637.605 us; speedup vs baseline: 1.1314x; 1.0649x over previous
//
#include <hip/hip_runtime.h>
#include <hip/hip_bf16.h>

#define N_NODES 170000
#define N_EDGES 1200000
#define SCAN_PAD 171008          // 167 blocks * 1024
#define NB_SCAN 167
#define NXCD 8

typedef short bf16x8 __attribute__((ext_vector_type(8)));
typedef float f32x4 __attribute__((ext_vector_type(4)));

__device__ __forceinline__ void bf_split(float v, __hip_bfloat16& h, __hip_bfloat16& l)
{
    h = __float2bfloat16(v);
    l = __float2bfloat16(v - __bfloat162float(h));
}

// XCD id (0..7), wave-uniform. HW_REG_XCC_ID verified on gfx950 (learn_hip m09).
__device__ __forceinline__ int xcc_id()
{
    int x;
    asm volatile("s_getreg_b32 %0, hwreg(HW_REG_XCC_ID)" : "=s"(x));
    return x & (NXCD - 1);
}

// ---------------- histogram: per-XCD privatized counts (L2-local atomics) -----
// Device-scope atomics are 32B fabric transactions at the memory-side coherence
// point (measured: WRITE_SIZE = 2.4M*32B, the session bottleneck). Workgroup-
// scope atomics execute in the issuing XCD's own TCC. Privatizing the histogram
// per XCD (cnt8[xcd][2N], indexed via HW_REG_XCC_ID) keeps every RMW L2-local;
// a cheap N-wide reduce sums the copies. rank = (xcd<<24)|local_rank keeps the
// atomic-free scatter correct via the per-(node,xcd) offset table xoff.
__global__ __launch_bounds__(256) void hist_kernel(
    const int* __restrict__ src, const int* __restrict__ dst,
    int* __restrict__ cnt8, int* __restrict__ rank, int nedges)
{
    int i = blockIdx.x * 256 + threadIdx.x;
    int x = xcc_id();
    int* base = cnt8 + (size_t)x * 2 * N_NODES;
    if (i < nedges) {
        __hip_atomic_fetch_add(&base[src[i]], 1, __ATOMIC_RELAXED,
                               __HIP_MEMORY_SCOPE_WORKGROUP);
        int r = __hip_atomic_fetch_add(&base[N_NODES + dst[i]], 1, __ATOMIC_RELAXED,
                                       __HIP_MEMORY_SCOPE_WORKGROUP);
        rank[i] = (x << 24) | r;
    }
}

// ---------------- sum 8 XCD copies -> totals + norms ----------------
__global__ __launch_bounds__(256) void reduce_norm_kernel(
    const int* __restrict__ cnt8, int* __restrict__ cnt_in_tot,
    float* __restrict__ norm_out, float* __restrict__ norm_in, int n)
{
    int v = blockIdx.x * 256 + threadIdx.x;
    if (v >= n) return;
    int so = 0, si = 0;
    #pragma unroll
    for (int x = 0; x < NXCD; x++) {
        so += cnt8[(size_t)x * 2 * N_NODES + v];
        si += cnt8[(size_t)x * 2 * N_NODES + N_NODES + v];
    }
    cnt_in_tot[v] = si;
    norm_out[v] = rsqrtf(fmaxf((float)so, 1.0f));
    norm_in[v]  = rsqrtf(fmaxf((float)si, 1.0f));
}

// ---------------- per-(node,xcd) scatter offsets ----------------
__global__ __launch_bounds__(256) void xoff_kernel(
    const int* __restrict__ cnt8, const int* __restrict__ row_start,
    int* __restrict__ xoff, int n)
{
    int v = blockIdx.x * 256 + threadIdx.x;
    if (v >= n) return;
    int base = row_start[v];
    #pragma unroll
    for (int x = 0; x < NXCD; x++) {
        xoff[(size_t)x * N_NODES + v] = base;
        base += cnt8[(size_t)x * 2 * N_NODES + N_NODES + v];
    }
}

// ---------------- fp32 -> bf16 row cast (feat) ----------------
__global__ __launch_bounds__(256) void f2bf_kernel(
    const float* __restrict__ in, __hip_bfloat16* __restrict__ outp, int n8)
{
    int i = blockIdx.x * 256 + threadIdx.x;
    if (i >= n8) return;
    float4 a = *(const float4*)&in[(size_t)i * 8];
    float4 b = *(const float4*)&in[(size_t)i * 8 + 4];
    float4 packed;
    __hip_bfloat162* p = (__hip_bfloat162*)&packed;
    p[0].x = __float2bfloat16(a.x); p[0].y = __float2bfloat16(a.y);
    p[1].x = __float2bfloat16(a.z); p[1].y = __float2bfloat16(a.w);
    p[2].x = __float2bfloat16(b.x); p[2].y = __float2bfloat16(b.y);
    p[3].x = __float2bfloat16(b.z); p[3].y = __float2bfloat16(b.w);
    *(float4*)&outp[(size_t)i * 8] = packed;
}

// ---------------- W (K x Nout fp32) -> transposed split planes Wt[n][k] bf16 ----------------
__global__ __launch_bounds__(256) void wsplit_kernel(
    const float* __restrict__ W, int nout,
    __hip_bfloat16* __restrict__ Whi, __hip_bfloat16* __restrict__ Wlo)
{
    int i = blockIdx.x * 256 + threadIdx.x;   // over 128*nout
    if (i >= 128 * nout) return;
    int k = i / nout, n = i - k * nout;
    float v = W[i];
    __hip_bfloat16 h, l;
    bf_split(v, h, l);
    Whi[n * 128 + k] = h;
    Wlo[n * 128 + k] = l;
}

// ---------------- 3-phase exclusive scan of cnt_in -> row_start ----------------
__global__ __launch_bounds__(256) void scan1_kernel(
    const int* __restrict__ in, int* __restrict__ partial,
    int* __restrict__ blockSums, int n)
{
    __shared__ int sdata[256];
    int t = threadIdx.x;
    int base = blockIdx.x * 1024 + t * 4;
    int4 v = make_int4(0, 0, 0, 0);
    if (base + 3 < n) v = *(const int4*)&in[base];
    else {
        if (base + 0 < n) v.x = in[base + 0];
        if (base + 1 < n) v.y = in[base + 1];
        if (base + 2 < n) v.z = in[base + 2];
        if (base + 3 < n) v.w = in[base + 3];
    }
    int tsum = v.x + v.y + v.z + v.w;
    sdata[t] = tsum;
    __syncthreads();
    for (int off = 1; off < 256; off <<= 1) {
        int add = 0;
        if (t >= off) add = sdata[t - off];
        __syncthreads();
        if (t >= off) sdata[t] += add;
        __syncthreads();
    }
    int excl = sdata[t] - tsum;
    int4 o;
    o.x = excl;
    o.y = o.x + v.x;
    o.z = o.y + v.y;
    o.w = o.z + v.z;
    *(int4*)&partial[base] = o;   // partial buffer padded to SCAN_PAD+4
    if (t == 255) blockSums[blockIdx.x] = sdata[255];
}

__global__ __launch_bounds__(256) void scan2_kernel(int* __restrict__ blockSums, int nb)
{
    __shared__ int sdata[256];
    int t = threadIdx.x;
    int val = (t < nb) ? blockSums[t] : 0;
    sdata[t] = val;
    __syncthreads();
    for (int off = 1; off < 256; off <<= 1) {
        int add = 0;
        if (t >= off) add = sdata[t - off];
        __syncthreads();
        if (t >= off) sdata[t] += add;
        __syncthreads();
    }
    if (t < nb) blockSums[t] = sdata[t] - val;   // exclusive
}

__global__ __launch_bounds__(256) void scan3_kernel(
    int* __restrict__ row_start, const int* __restrict__ blockSums)
{
    int off = blockSums[blockIdx.x];
    int base = blockIdx.x * 1024 + threadIdx.x * 4;
    int4 v = *(const int4*)&row_start[base];
    v.x += off; v.y += off; v.z += off; v.w += off;
    *(int4*)&row_start[base] = v;
}

// ---------------- scatter src ids into dst-sorted CSR (atomic-free) ----------------
// slot = xoff[xcd][dst] + local_rank; unique by construction.
__global__ __launch_bounds__(256) void scatter_kernel(
    const int* __restrict__ src, const int* __restrict__ dst,
    const int* __restrict__ rank, const int* __restrict__ xoff,
    int* __restrict__ csr, int nedges)
{
    int i = blockIdx.x * 256 + threadIdx.x;
    if (i < nedges) {
        int rv = rank[i];
        csr[xoff[(size_t)(rv >> 24) * N_NODES + dst[i]] + (rv & 0xFFFFFF)] = src[i];
    }
}

// ---------------- pull aggregation: 16-lane group per dst row, bf16 features ----
// Accumulates fp32. For W=128 emits SPLIT bf16 planes (hi+lo ~ fp32 precision,
// feeds the MFMA GEMM); for W=64 (final layer) emits fp32 + bias.
template<int W, bool SCALE_SRC, bool SPLIT_OUT, bool BIAS>
__global__ __launch_bounds__(256) void gather_kernel(
    const __hip_bfloat16* __restrict__ h, const int* __restrict__ csr,
    const int* __restrict__ row_start, const float* __restrict__ norm_out,
    const float* __restrict__ norm_in, const float* __restrict__ bias,
    float* __restrict__ outf, __hip_bfloat16* __restrict__ ohi,
    __hip_bfloat16* __restrict__ olo)
{
    int tid = blockIdx.x * 256 + threadIdx.x;
    int row = tid >> 4;                 // 16 lanes per row
    int l = threadIdx.x & 15;           // lane within group
    int gbase = threadIdx.x & 48;       // group's base lane within the wave
    if (row >= N_NODES) return;
    int beg = row_start[row];
    int end = row_start[row + 1];
    float acc[8] = {};
    for (int j = beg; j < end; j += 16) {
        int cnt = min(16, end - j);
        int sv = 0;
        float nv = 0.f;
        if (j + l < end) {
            sv = csr[j + l];                       // coalesced edge-id load
            if (SCALE_SRC) nv = norm_out[sv];
        }
        for (int i = 0; i < cnt; i++) {
            int s = __shfl(sv, gbase + i);
            if (W == 128) {
                float4 raw = *(const float4*)(h + (size_t)s * 128 + l * 8);
                const __hip_bfloat162* pp = (const __hip_bfloat162*)&raw;
                float2 f0 = __bfloat1622float2(pp[0]);
                float2 f1 = __bfloat1622float2(pp[1]);
                float2 f2 = __bfloat1622float2(pp[2]);
                float2 f3 = __bfloat1622float2(pp[3]);
                if (SCALE_SRC) {
                    float sc = __shfl(nv, gbase + i);
                    acc[0] += f0.x * sc; acc[1] += f0.y * sc;
                    acc[2] += f1.x * sc; acc[3] += f1.y * sc;
                    acc[4] += f2.x * sc; acc[5] += f2.y * sc;
                    acc[6] += f3.x * sc; acc[7] += f3.y * sc;
                } else {
                    acc[0] += f0.x; acc[1] += f0.y;
                    acc[2] += f1.x; acc[3] += f1.y;
                    acc[4] += f2.x; acc[5] += f2.y;
                    acc[6] += f3.x; acc[7] += f3.y;
                }
            } else {
                float2 raw = *(const float2*)(h + (size_t)s * 64 + l * 4);
                const __hip_bfloat162* pp = (const __hip_bfloat162*)&raw;
                float2 f0 = __bfloat1622float2(pp[0]);
                float2 f1 = __bfloat1622float2(pp[1]);
                acc[0] += f0.x; acc[1] += f0.y;
                acc[2] += f1.x; acc[3] += f1.y;
            }
        }
    }
    float ni = norm_in[row];
    if (W == 128 && SPLIT_OUT) {
        float4 ph, pl;
        __hip_bfloat16* hp = (__hip_bfloat16*)&ph;
        __hip_bfloat16* lp = (__hip_bfloat16*)&pl;
        #pragma unroll
        for (int j = 0; j < 8; j++) bf_split(acc[j] * ni, hp[j], lp[j]);
        *(float4*)(ohi + (size_t)row * 128 + l * 8) = ph;
        *(float4*)(olo + (size_t)row * 128 + l * 8) = pl;
    } else if (W == 64) {
        float4 o0 = make_float4(acc[0] * ni, acc[1] * ni, acc[2] * ni, acc[3] * ni);
        if (BIAS) {
            float4 b = *(const float4*)&bias[l * 4];
            o0.x += b.x; o0.y += b.y; o0.z += b.z; o0.w += b.w;
        }
        *(float4*)&outf[(size_t)row * 64 + l * 4] = o0;
    }
}

// ---------------- MFMA GEMM: out = act(A @ W + b) * rowscale ----------------
// A in split bf16 planes (hi+lo ~ fp32), Wt in transposed split planes [n][k].
// 3-MFMA split product: hi*hi + lo*hi + hi*lo (lo*lo dropped, ~2^-16 rel).
// Per wave: two 16-row tiles x NT 16-col tiles, K=128 in 4 chunks of 32.
// No LDS, no barriers; W planes stay L1/L2-resident.
// #pragma unroll 1 on kc: prevents full-unroll load hoisting (R1 spill lesson).
template<int NT, bool RELU, bool BIAS, bool RS, bool SPLIT_OUT>
__global__ __launch_bounds__(256) void mfma_matmul_kernel(
    const __hip_bfloat16* __restrict__ Ahi, const __hip_bfloat16* __restrict__ Alo,
    const __hip_bfloat16* __restrict__ Wthi, const __hip_bfloat16* __restrict__ Wtlo,
    const float* __restrict__ bias, const float* __restrict__ rowscale,
    __hip_bfloat16* __restrict__ outhi, __hip_bfloat16* __restrict__ outlo,
    int nrows)
{
    const int OUTW = NT * 16;
    const int wave = threadIdx.x >> 6;
    const int lane = threadIdx.x & 63;
    const int n = lane & 15;       // col within tile (B/D); also row within tile for A
    const int q = lane >> 4;       // quad
    const int r0 = blockIdx.x * 128 + wave * 32;
    if (r0 >= nrows) return;
    const bool t1 = (r0 + 16) < nrows;          // nrows % 16 == 0 -> tiles are full
    const size_t a0off = (size_t)(r0 + n) * 128 + q * 8;
    const size_t a1off = (size_t)(t1 ? (r0 + 16 + n) : (r0 + n)) * 128 + q * 8;
    const size_t bbase = (size_t)n * 128 + q * 8;

    f32x4 acc0[NT], acc1[NT];
    const f32x4 zero = {0.f, 0.f, 0.f, 0.f};
    #pragma unroll
    for (int ct = 0; ct < NT; ct++) { acc0[ct] = zero; acc1[ct] = zero; }

    #pragma unroll 1
    for (int kc = 0; kc < 4; kc++) {
        bf16x8 ah0 = *(const bf16x8*)(Ahi + a0off + kc * 32);
        bf16x8 al0 = *(const bf16x8*)(Alo + a0off + kc * 32);
        bf16x8 ah1 = *(const bf16x8*)(Ahi + a1off + kc * 32);
        bf16x8 al1 = *(const bf16x8*)(Alo + a1off + kc * 32);
        #pragma unroll
        for (int ct = 0; ct < NT; ct++) {
            bf16x8 bh = *(const bf16x8*)(Wthi + (size_t)ct * 2048 + bbase + kc * 32);
            bf16x8 bl = *(const bf16x8*)(Wtlo + (size_t)ct * 2048 + bbase + kc * 32);
            acc0[ct] = __builtin_amdgcn_mfma_f32_16x16x32_bf16(ah0, bh, acc0[ct], 0, 0, 0);
            acc0[ct] = __builtin_amdgcn_mfma_f32_16x16x32_bf16(al0, bh, acc0[ct], 0, 0, 0);
            acc0[ct] = __builtin_amdgcn_mfma_f32_16x16x32_bf16(ah0, bl, acc0[ct], 0, 0, 0);
            acc1[ct] = __builtin_amdgcn_mfma_f32_16x16x32_bf16(ah1, bh, acc1[ct], 0, 0, 0);
            acc1[ct] = __builtin_amdgcn_mfma_f32_16x16x32_bf16(al1, bh, acc1[ct], 0, 0, 0);
            acc1[ct] = __builtin_amdgcn_mfma_f32_16x16x32_bf16(ah1, bl, acc1[ct], 0, 0, 0);
        }
    }

    float bcol[NT];
    #pragma unroll
    for (int ct = 0; ct < NT; ct++) bcol[ct] = BIAS ? bias[ct * 16 + n] : 0.f;

    // tile 0: rows r0 + q*4 + r
    #pragma unroll
    for (int r = 0; r < 4; r++) {
        int grow = r0 + q * 4 + r;
        float rs = RS ? rowscale[grow] : 1.f;
        #pragma unroll
        for (int ct = 0; ct < NT; ct++) {
            float v = acc0[ct][r] + bcol[ct];
            if (RELU) v = fmaxf(v, 0.f);
            v *= rs;
            size_t o = (size_t)grow * OUTW + ct * 16 + n;
            if (SPLIT_OUT) {
                __hip_bfloat16 h, l;
                bf_split(v, h, l);
                outhi[o] = h; outlo[o] = l;
            } else {
                outhi[o] = __float2bfloat16(v);
            }
        }
    }
    if (t1) {
        #pragma unroll
        for (int r = 0; r < 4; r++) {
            int grow = r0 + 16 + q * 4 + r;
            float rs = RS ? rowscale[grow] : 1.f;
            #pragma unroll
            for (int ct = 0; ct < NT; ct++) {
                float v = acc1[ct][r] + bcol[ct];
                if (RELU) v = fmaxf(v, 0.f);
                v *= rs;
                size_t o = (size_t)grow * OUTW + ct * 16 + n;
                if (SPLIT_OUT) {
                    __hip_bfloat16 h, l;
                    bf_split(v, h, l);
                    outhi[o] = h; outlo[o] = l;
                } else {
                    outhi[o] = __float2bfloat16(v);
                }
            }
        }
    }
}

extern "C" void kernel_launch(void* const* d_in, const int* in_sizes, int n_in,
                              void* d_out, int out_size, void* d_ws, size_t ws_size,
                              hipStream_t stream)
{
    const float* feat = (const float*)d_in[0];
    const int* src    = (const int*)d_in[1];
    const int* dst    = (const int*)d_in[2];
    const float* W0   = (const float*)d_in[3];
    const float* b0   = (const float*)d_in[4];
    const float* W1   = (const float*)d_in[5];
    const float* b1   = (const float*)d_in[6];
    const float* W2   = (const float*)d_in[7];
    const float* b2   = (const float*)d_in[8];
    float* out = (float*)d_out;

    const int N = N_NODES;
    const int E = N_EDGES;

    // ---- workspace layout ----
    char* ws = (char*)d_ws;
    float* norm_out = (float*)ws;                    // N
    float* norm_in  = norm_out + N;                  // N
    int* cnt_in_tot = (int*)(norm_in + N);           // N
    int* row_start  = cnt_in_tot + N;                // SCAN_PAD + 4
    int* blockSums  = row_start + (SCAN_PAD + 4);    // 268 (keeps 16B alignment)
    int* csr        = blockSums + 268;               // E
    __hip_bfloat16* Wt0hi = (__hip_bfloat16*)(csr + E);   // 16384 each
    __hip_bfloat16* Wt0lo = Wt0hi + 16384;
    __hip_bfloat16* Wt1hi = Wt0lo + 16384;
    __hip_bfloat16* Wt1lo = Wt1hi + 16384;
    __hip_bfloat16* Wt2hi = Wt1lo + 16384;           // 8192 each
    __hip_bfloat16* Wt2lo = Wt2hi + 8192;
    __hip_bfloat16* bfbuf = Wt2lo + 8192;            // N*128 (featbf -> h1bf -> tbf)
    __hip_bfloat16* Ahi   = bfbuf + (size_t)N * 128; // N*128
    __hip_bfloat16* Alo   = Ahi + (size_t)N * 128;   // N*128
    // CSR-build scratch aliases A planes (both are dead until gather1, which
    // runs strictly after scatter in stream order):
    //   rank (E ints, 4.8MB)          -> on Ahi
    //   cnt8 (8*2N ints, 10.88MB)     -> on Alo
    //   xoff (8*N ints, 5.44MB)       -> on Alo after cnt8
    int* rank = (int*)Ahi;
    int* cnt8 = (int*)Alo;
    int* xoff = cnt8 + (size_t)NXCD * 2 * N;

    // ---- CSR build + casts/splits ----
    hipMemsetAsync(cnt8, 0, (size_t)NXCD * 2 * N * sizeof(int), stream);
    hist_kernel<<<(E + 255) / 256, 256, 0, stream>>>(src, dst, cnt8, rank, E);
    reduce_norm_kernel<<<(N + 255) / 256, 256, 0, stream>>>(
        cnt8, cnt_in_tot, norm_out, norm_in, N);
    scan1_kernel<<<NB_SCAN, 256, 0, stream>>>(cnt_in_tot, row_start, blockSums, N);
    scan2_kernel<<<1, 256, 0, stream>>>(blockSums, NB_SCAN);
    scan3_kernel<<<NB_SCAN, 256, 0, stream>>>(row_start, blockSums);
    xoff_kernel<<<(N + 255) / 256, 256, 0, stream>>>(cnt8, row_start, xoff, N);
    scatter_kernel<<<(E + 255) / 256, 256, 0, stream>>>(src, dst, rank, xoff, csr, E);
    f2bf_kernel<<<(N * 16 + 255) / 256, 256, 0, stream>>>(feat, bfbuf, N * 16);
    wsplit_kernel<<<64, 256, 0, stream>>>(W0, 128, Wt0hi, Wt0lo);
    wsplit_kernel<<<64, 256, 0, stream>>>(W1, 128, Wt1hi, Wt1lo);
    wsplit_kernel<<<32, 256, 0, stream>>>(W2, 64, Wt2hi, Wt2lo);

    const int gatherBlocks = (N * 16 + 255) / 256;   // 16 lanes/row
    const int mmBlocks = (N + 127) / 128;            // 128 rows/block (2 tiles/wave)

    // ---- Layer 1: agg(featbf*no)*ni -> A split; relu(A@W0+b0)*no -> h1bf
    gather_kernel<128, true, true, false><<<gatherBlocks, 256, 0, stream>>>(
        bfbuf, csr, row_start, norm_out, norm_in, nullptr, nullptr, Ahi, Alo);
    mfma_matmul_kernel<8, true, true, true, false><<<mmBlocks, 256, 0, stream>>>(
        Ahi, Alo, Wt0hi, Wt0lo, b0, norm_out, bfbuf, nullptr, N);

    // ---- Layer 2: agg(h1bf)*ni -> A split; relu(A@W1+b1)*no -> A split (in-place)
    gather_kernel<128, false, true, false><<<gatherBlocks, 256, 0, stream>>>(
        bfbuf, csr, row_start, nullptr, norm_in, nullptr, nullptr, Ahi, Alo);
    mfma_matmul_kernel<8, true, true, true, true><<<mmBlocks, 256, 0, stream>>>(
        Ahi, Alo, Wt1hi, Wt1lo, b1, norm_out, Ahi, Alo, N);

    // ---- Layer 3 (commuted): tbf = bf16(h2@W2); out = agg(tbf)*ni + b2
    mfma_matmul_kernel<4, false, false, false, false><<<mmBlocks, 256, 0, stream>>>(
        Ahi, Alo, Wt2hi, Wt2lo, nullptr, nullptr, bfbuf, nullptr, N);
    gather_kernel<64, false, false, true><<<gatherBlocks, 256, 0, stream>>>(
        bfbuf, csr, row_start, nullptr, norm_in, b2, out, nullptr, nullptr);
}